// Round 1
// baseline (9247.477 us; speedup 1.0000x reference)
//
#include <hip/hip_runtime.h>

#define B_SZ 512
#define S_SZ 256
#define D_SZ 512
#define H_SZ 512

typedef __bf16 bf16x8 __attribute__((ext_vector_type(8)));
typedef float f32x4 __attribute__((ext_vector_type(4)));

// ---------------- ws layout (bytes) ----------------
// [0, 512)                  : 8 group barrier counters (64B stride)
// [512, 512+1048576)        : state parity 0: h0 (512x512 bf16) then cf0 (c*f_att, bf16)
// [+1048576, +2097152)      : state parity 1: h1, cf1
// [2097664, +4194304)       : GwT 4*512*1024 bf16: (g, j, k); k<512 -> U_g[k][j], else V_g[k-512][j]
// [6291968, +524288)        : WeT 512*512 bf16: (j, k) = W_e[k][j]
#define STATE_PAR_ELEMS (2 * H_SZ * B_SZ)  // 524288 bf16 per parity (h then cf)
#define GWT_OFF_BYTES 2097664
#define WET_OFF_BYTES 6291968

__device__ __forceinline__ float sigmoidf_(float v) {
    return 1.f / (1.f + __expf(-v));
}
__device__ __forceinline__ float tanhf_(float v) {
    // 1 - 2/(1+e^{2v}) : saturates cleanly to +/-1 without inf/inf NaN
    return 1.f - 2.f / (1.f + __expf(2.f * v));
}

__global__ __launch_bounds__(256) void prep_weights(
    const float* __restrict__ We,
    const float* __restrict__ Ui, const float* __restrict__ Vi,
    const float* __restrict__ Uf, const float* __restrict__ Vf,
    const float* __restrict__ Uc, const float* __restrict__ Vc,
    const float* __restrict__ Uo, const float* __restrict__ Vo,
    __bf16* __restrict__ GwT, __bf16* __restrict__ WeT)
{
    const int bid = blockIdx.x;
    const int tid = threadIdx.x;
    if (bid < 2048) {
        const int g = bid >> 9;
        const int j = bid & 511;
        const float* U = (g == 0) ? Ui : (g == 1) ? Uf : (g == 2) ? Uc : Uo;
        const float* V = (g == 0) ? Vi : (g == 1) ? Vf : (g == 2) ? Vc : Vo;
        __bf16* dst = GwT + ((size_t)(g * 512 + j) << 10);
        for (int k = tid; k < 1024; k += 256) {
            float v = (k < 512) ? U[k * 512 + j] : V[(k - 512) * 512 + j];
            dst[k] = (__bf16)v;
        }
    } else {
        const int j = bid - 2048;
        __bf16* dst = WeT + ((size_t)j << 9);
        for (int k = tid; k < 512; k += 256) {
            dst[k] = (__bf16)We[k * 512 + j];
        }
    }
}

// Persistent recurrent kernel.
// Grid = 256 WGs x 256 threads. LDS ~148.7KB -> exactly 1 WG/CU -> all 256 resident.
// WG (rblk = bid&7, cblk = bid>>3) owns batch rows [rblk*64, +64) and hidden cols
// [cblk*16, +16). Sync groups = 32 WGs sharing rblk (8 independent barriers).
__global__ __launch_bounds__(256, 1) void lstm_persist(
    const float* __restrict__ x, const float* __restrict__ tseq,
    const float* __restrict__ b_i, const float* __restrict__ b_f,
    const float* __restrict__ b_c, const float* __restrict__ b_o,
    const float* __restrict__ b_e,
    const __bf16* __restrict__ GwT, const __bf16* __restrict__ WeT,
    __bf16* __restrict__ state, int* __restrict__ cnts,
    float* __restrict__ out)
{
    // column-major per-column weights, stride padded 1024->1032 / 512->520
    // (stride % 32 dwords == 4 -> ~2-way bank aliasing on ds_read_b128 = free)
    __shared__ __align__(16) __bf16 wlds[4][16][1032];
    __shared__ __align__(16) __bf16 welds[16][520];

    const int tid = threadIdx.x;
    const int bid = blockIdx.x;
    const int rblk = bid & 7;
    const int cblk = bid >> 3;
    const int j0 = cblk << 4;
    const int wave = tid >> 6;
    const int lane = tid & 63;
    const int alr = lane & 15;   // A-frag row / B-frag col / C col
    const int hq = lane >> 4;    // k-subgroup

    // ---- stage weight slice into LDS (once) ----
    for (int e = tid * 8; e < 4 * 16 * 1024; e += 256 * 8) {
        const int g = e >> 14;
        const int j = (e >> 10) & 15;
        const int k = e & 1023;
        *(uint4*)&wlds[g][j][k] = *(const uint4*)&GwT[((size_t)(g * 512 + j0 + j) << 10) + k];
    }
    for (int e = tid * 8; e < 16 * 512; e += 256 * 8) {
        const int j = e >> 9;
        const int k = e & 511;
        *(uint4*)&welds[j][k] = *(const uint4*)&WeT[((size_t)(j0 + j) << 9) + k];
    }
    __syncthreads();

    const int jj = j0 + alr;
    const float Bi = b_i[jj], Bf = b_f[jj], Bc = b_c[jj], Bo = b_o[jj], Be = b_e[jj];

    const int arow = rblk * 64 + wave * 16 + alr;     // batch row for A fragments
    const float* xrow = x + (size_t)arow * S_SZ * D_SZ;
    const size_t hoff = (size_t)arow * H_SZ;
    const int bout0 = rblk * 64 + wave * 16 + hq * 4; // C/D rows: (lane>>4)*4 + e

    for (int t = 0; t < S_SZ; ++t) {
        const __bf16* hp = state + (size_t)(t & 1) * STATE_PAR_ELEMS;
        const __bf16* cp = hp + (size_t)H_SZ * B_SZ;
        __bf16* hnx = state + (size_t)((t + 1) & 1) * STATE_PAR_ELEMS;
        __bf16* cnx = hnx + (size_t)H_SZ * B_SZ;

        f32x4 a0 = {0,0,0,0}, a1 = {0,0,0,0}, a2 = {0,0,0,0}, a3 = {0,0,0,0}, a4 = {0,0,0,0};

        const float* xp = xrow + (size_t)t * D_SZ;
        const int kbase = hq * 8;

        // gates, x @ U part (K = 0..512)
        #pragma unroll 4
        for (int kk = 0; kk < 16; ++kk) {
            const int k = kk * 32 + kbase;
            f32x4 u = *(const f32x4*)(xp + k);
            f32x4 v = *(const f32x4*)(xp + k + 4);
            bf16x8 a;
            a[0] = (__bf16)u[0]; a[1] = (__bf16)u[1]; a[2] = (__bf16)u[2]; a[3] = (__bf16)u[3];
            a[4] = (__bf16)v[0]; a[5] = (__bf16)v[1]; a[6] = (__bf16)v[2]; a[7] = (__bf16)v[3];
            bf16x8 w0 = *(const bf16x8*)&wlds[0][alr][k];
            bf16x8 w1 = *(const bf16x8*)&wlds[1][alr][k];
            bf16x8 w2 = *(const bf16x8*)&wlds[2][alr][k];
            bf16x8 w3 = *(const bf16x8*)&wlds[3][alr][k];
            a0 = __builtin_amdgcn_mfma_f32_16x16x32_bf16(a, w0, a0, 0, 0, 0);
            a1 = __builtin_amdgcn_mfma_f32_16x16x32_bf16(a, w1, a1, 0, 0, 0);
            a2 = __builtin_amdgcn_mfma_f32_16x16x32_bf16(a, w2, a2, 0, 0, 0);
            a3 = __builtin_amdgcn_mfma_f32_16x16x32_bf16(a, w3, a3, 0, 0, 0);
        }
        // gates, h @ V part (K = 512..1024)
        #pragma unroll 4
        for (int kk = 0; kk < 16; ++kk) {
            const int k = kk * 32 + kbase;
            bf16x8 a = *(const bf16x8*)(hp + hoff + k);
            bf16x8 w0 = *(const bf16x8*)&wlds[0][alr][512 + k];
            bf16x8 w1 = *(const bf16x8*)&wlds[1][alr][512 + k];
            bf16x8 w2 = *(const bf16x8*)&wlds[2][alr][512 + k];
            bf16x8 w3 = *(const bf16x8*)&wlds[3][alr][512 + k];
            a0 = __builtin_amdgcn_mfma_f32_16x16x32_bf16(a, w0, a0, 0, 0, 0);
            a1 = __builtin_amdgcn_mfma_f32_16x16x32_bf16(a, w1, a1, 0, 0, 0);
            a2 = __builtin_amdgcn_mfma_f32_16x16x32_bf16(a, w2, a2, 0, 0, 0);
            a3 = __builtin_amdgcn_mfma_f32_16x16x32_bf16(a, w3, a3, 0, 0, 0);
        }
        // ctilde: (c_{t-1} * f_att_t) @ W_e   (cp is pre-scaled)
        #pragma unroll 4
        for (int kk = 0; kk < 16; ++kk) {
            const int k = kk * 32 + kbase;
            bf16x8 a = *(const bf16x8*)(cp + hoff + k);
            bf16x8 w = *(const bf16x8*)&welds[alr][k];
            a4 = __builtin_amdgcn_mfma_f32_16x16x32_bf16(a, w, a4, 0, 0, 0);
        }

        // elementwise + state writeback. C/D: col = lane&15, row = (lane>>4)*4 + e
        #pragma unroll
        for (int e = 0; e < 4; ++e) {
            const int b = bout0 + e;
            float it = sigmoidf_(a0[e] + Bi);
            float ft = sigmoidf_(a1[e] + Bf);
            float gt = tanhf_(a2[e] + Bc);
            float ot = sigmoidf_(a3[e] + Bo);
            float ctl = tanhf_(a4[e] + Be);
            float cv = ft * ctl + it * gt;
            float hv = ot * tanhf_(cv);
            out[((size_t)b * S_SZ + t) * H_SZ + jj] = hv;
            hnx[(size_t)b * H_SZ + jj] = (__bf16)hv;
            float fa = (t + 1 < S_SZ) ? tseq[b * S_SZ + t + 1] : 0.f;
            cnx[(size_t)b * H_SZ + jj] = (__bf16)(cv * fa);
            if (t == S_SZ - 1) {
                const size_t base = (size_t)B_SZ * S_SZ * H_SZ;
                out[base + (size_t)b * H_SZ + jj] = hv;
                out[base + (size_t)B_SZ * H_SZ + (size_t)b * H_SZ + jj] = cv;
            }
        }

        // per-row-group barrier (32 WGs sharing rblk); monotonic counter, no reset
        if (t < S_SZ - 1) {
            __syncthreads();
            if (tid == 0) {
                __threadfence();  // release: flush our group's h/cf writes
                __hip_atomic_fetch_add(&cnts[rblk * 16], 1, __ATOMIC_RELEASE,
                                       __HIP_MEMORY_SCOPE_AGENT);
                const int target = 32 * (t + 1);
                while (__hip_atomic_load(&cnts[rblk * 16], __ATOMIC_RELAXED,
                                         __HIP_MEMORY_SCOPE_AGENT) < target) {
                    __builtin_amdgcn_s_sleep(2);
                }
            }
            __syncthreads();
            __threadfence();  // acquire: invalidate stale L1/L2 lines before reading peers' state
        }
    }
}

extern "C" void kernel_launch(void* const* d_in, const int* in_sizes, int n_in,
                              void* d_out, int out_size, void* d_ws, size_t ws_size,
                              hipStream_t stream) {
    const float* x  = (const float*)d_in[0];
    const float* ts = (const float*)d_in[1];
    const float* We = (const float*)d_in[2];
    const float* be = (const float*)d_in[3];
    const float* Ui = (const float*)d_in[4];
    const float* Vi = (const float*)d_in[5];
    const float* bi = (const float*)d_in[6];
    const float* Uf = (const float*)d_in[7];
    const float* Vf = (const float*)d_in[8];
    const float* bf = (const float*)d_in[9];
    const float* Uc = (const float*)d_in[10];
    const float* Vc = (const float*)d_in[11];
    const float* bc = (const float*)d_in[12];
    const float* Uo = (const float*)d_in[13];
    const float* Vo = (const float*)d_in[14];
    const float* bo = (const float*)d_in[15];

    char* ws = (char*)d_ws;
    int* cnts = (int*)ws;
    __bf16* state = (__bf16*)(ws + 512);
    __bf16* GwT = (__bf16*)(ws + GWT_OFF_BYTES);
    __bf16* WeT = (__bf16*)(ws + WET_OFF_BYTES);

    // zero barrier counters + parity-0 state (h0 = c0 = 0)
    hipMemsetAsync(ws, 0, 512 + 2 * 524288, stream);
    prep_weights<<<2560, 256, 0, stream>>>(We, Ui, Vi, Uf, Vf, Uc, Vc, Uo, Vo, GwT, WeT);
    lstm_persist<<<256, 256, 0, stream>>>(x, ts, bi, bf, bc, bo, be, GwT, WeT,
                                          state, cnts, (float*)d_out);
}

// Round 2
// 4790.620 us; speedup vs baseline: 1.9303x; 1.9303x over previous
//
#include <hip/hip_runtime.h>

#define B_SZ 512
#define S_SZ 256
#define D_SZ 512
#define H_SZ 512

typedef __bf16 bf16x8 __attribute__((ext_vector_type(8)));
typedef __bf16 bf16x4 __attribute__((ext_vector_type(4)));
typedef float f32x4 __attribute__((ext_vector_type(4)));
typedef unsigned long long u64;

// ---------------- ws layout (bytes) ----------------
// [0, 512)                  : 8 group barrier counters (64B stride)
// [512, 512+1048576)        : state parity 0: h0 (512x512 bf16) then cf0 (c*f_att, bf16)
// [+1048576, +2097152)      : state parity 1: h1, cf1
// [2097664, +4194304)       : GwT 4*512*1024 bf16: (g, j, k); k<512 -> U_g[k][j], else V_g[k-512][j]
// [6291968, +524288)        : WeT 512*512 bf16: (j, k) = W_e[k][j]
#define STATE_PAR_ELEMS (2 * H_SZ * B_SZ)
#define GWT_OFF_BYTES 2097664
#define WET_OFF_BYTES 6291968

__device__ __forceinline__ float sigmoidf_(float v) {
    return 1.f / (1.f + __expf(-v));
}
__device__ __forceinline__ float tanhf_(float v) {
    return 1.f - 2.f / (1.f + __expf(2.f * v));
}

// coherent (LLC-level) 8-byte accesses: relaxed agent atomics compile to
// global_load/store_dwordx2 with sc0/sc1 bits -> bypass L1/L2, coherent at
// LLC across XCDs. NO cache-flush instructions (the round-1 killer).
__device__ __forceinline__ u64 coh_load(const u64* p) {
    return __hip_atomic_load(p, __ATOMIC_RELAXED, __HIP_MEMORY_SCOPE_AGENT);
}
__device__ __forceinline__ void coh_store(u64* p, u64 v) {
    __hip_atomic_store(p, v, __ATOMIC_RELAXED, __HIP_MEMORY_SCOPE_AGENT);
}

__global__ __launch_bounds__(256) void prep_weights(
    const float* __restrict__ We,
    const float* __restrict__ Ui, const float* __restrict__ Vi,
    const float* __restrict__ Uf, const float* __restrict__ Vf,
    const float* __restrict__ Uc, const float* __restrict__ Vc,
    const float* __restrict__ Uo, const float* __restrict__ Vo,
    __bf16* __restrict__ GwT, __bf16* __restrict__ WeT)
{
    const int bid = blockIdx.x;
    const int tid = threadIdx.x;
    if (bid < 2048) {
        const int g = bid >> 9;
        const int j = bid & 511;
        const float* U = (g == 0) ? Ui : (g == 1) ? Uf : (g == 2) ? Uc : Uo;
        const float* V = (g == 0) ? Vi : (g == 1) ? Vf : (g == 2) ? Vc : Vo;
        __bf16* dst = GwT + ((size_t)(g * 512 + j) << 10);
        for (int k = tid; k < 1024; k += 256) {
            float v = (k < 512) ? U[k * 512 + j] : V[(k - 512) * 512 + j];
            dst[k] = (__bf16)v;
        }
    } else {
        const int j = bid - 2048;
        __bf16* dst = WeT + ((size_t)j << 9);
        for (int k = tid; k < 512; k += 256) {
            dst[k] = (__bf16)We[k * 512 + j];
        }
    }
}

// Persistent recurrent kernel. Grid = 256 WGs x 256 threads, 1 WG/CU (132KB LDS).
// WG (rblk=bid&7, cblk=bid>>3) owns batch rows [rblk*64,+64) x hidden cols
// [cblk*16,+16). Weights for its 16 cols live in LDS (gates) + registers
// (W_e frags + gates k<256 frags) for all 256 steps.
// MFMA: A = weights (m=j), B = activations (n=batch) -> C holds 4 consecutive
// j per lane -> fully vectorized u64/f32x4 stores.
__global__ __launch_bounds__(256, 1) void lstm_persist(
    const float* __restrict__ x, const float* __restrict__ tseq,
    const float* __restrict__ b_i, const float* __restrict__ b_f,
    const float* __restrict__ b_c, const float* __restrict__ b_o,
    const float* __restrict__ b_e,
    const __bf16* __restrict__ GwT, const __bf16* __restrict__ WeT,
    __bf16* __restrict__ state, int* __restrict__ cnts,
    float* __restrict__ out)
{
    // stride 1032 elems = 516 dwords; within an 8-lane group banks spread
    // (alr*516)%32 = alr*4 -> 8 distinct banks, conflict-free per group
    __shared__ __align__(16) __bf16 wlds[4][16][1032];

    const int tid = threadIdx.x;
    const int bid = blockIdx.x;
    const int rblk = bid & 7;
    const int cblk = bid >> 3;
    const int j0 = cblk << 4;
    const int wave = tid >> 6;
    const int lane = tid & 63;
    const int alr = lane & 15;   // A: j-row ; B: batch-col ; C: batch-col
    const int hq = lane >> 4;    // k-subgroup / C j-quad
    const int kbase = hq * 8;

    // ---- stage gate-weight slice into LDS (once) ----
    for (int e = tid * 8; e < 4 * 16 * 1024; e += 256 * 8) {
        const int g = e >> 14;
        const int j = (e >> 10) & 15;
        const int k = e & 1023;
        *(uint4*)&wlds[g][j][k] = *(const uint4*)&GwT[((size_t)(g * 512 + j0 + j) << 10) + k];
    }
    __syncthreads();

    // ---- register-resident weight fragments ----
    bf16x8 wer[16];                       // W_e, all K (64 VGPR)
    const __bf16* wep = WeT + ((size_t)(j0 + alr) << 9) + kbase;
    #pragma unroll
    for (int kk = 0; kk < 16; ++kk) wer[kk] = *(const bf16x8*)(wep + kk * 32);

    bf16x8 wxr[8][4];                     // gates, k<256 (128 VGPR)
    #pragma unroll
    for (int kk = 0; kk < 8; ++kk)
        #pragma unroll
        for (int g = 0; g < 4; ++g)
            wxr[kk][g] = *(const bf16x8*)&wlds[g][alr][kk * 32 + kbase];

    // per-thread output coordinates
    const int brow = rblk * 64 + wave * 16 + alr;   // batch row (B operand + C col)
    const int jbase = j0 + hq * 4;                   // 4 consecutive j (C rows)
    const f32x4 Bi4 = *(const f32x4*)(b_i + jbase);
    const f32x4 Bf4 = *(const f32x4*)(b_f + jbase);
    const f32x4 Bc4 = *(const f32x4*)(b_c + jbase);
    const f32x4 Bo4 = *(const f32x4*)(b_o + jbase);
    const f32x4 Be4 = *(const f32x4*)(b_e + jbase);

    const float* xrow = x + (size_t)brow * S_SZ * D_SZ;
    const float* tsrow = tseq + (size_t)brow * S_SZ;
    const size_t hoff = (size_t)brow * H_SZ;         // elem offset of this row in state
    float* outrow = out + (size_t)brow * S_SZ * H_SZ + jbase;

    for (int t = 0; t < S_SZ; ++t) {
        const __bf16* hp = state + (size_t)(t & 1) * STATE_PAR_ELEMS;
        const __bf16* cp = hp + (size_t)H_SZ * B_SZ;
        __bf16* hnx = state + (size_t)((t + 1) & 1) * STATE_PAR_ELEMS;
        __bf16* cnx = hnx + (size_t)H_SZ * B_SZ;

        f32x4 a0 = {0,0,0,0}, a1 = {0,0,0,0}, a2 = {0,0,0,0}, a3 = {0,0,0,0}, a4 = {0,0,0,0};
        const float* xp = xrow + (size_t)t * D_SZ;

        // gates, x @ U part (K = 0..512): k<256 weights from regs, rest LDS
        #pragma unroll
        for (int kk = 0; kk < 16; ++kk) {
            const int k = kk * 32 + kbase;
            f32x4 u = *(const f32x4*)(xp + k);
            f32x4 v = *(const f32x4*)(xp + k + 4);
            bf16x8 a;
            a[0] = (__bf16)u[0]; a[1] = (__bf16)u[1]; a[2] = (__bf16)u[2]; a[3] = (__bf16)u[3];
            a[4] = (__bf16)v[0]; a[5] = (__bf16)v[1]; a[6] = (__bf16)v[2]; a[7] = (__bf16)v[3];
            if (kk < 8) {
                a0 = __builtin_amdgcn_mfma_f32_16x16x32_bf16(wxr[kk][0], a, a0, 0, 0, 0);
                a1 = __builtin_amdgcn_mfma_f32_16x16x32_bf16(wxr[kk][1], a, a1, 0, 0, 0);
                a2 = __builtin_amdgcn_mfma_f32_16x16x32_bf16(wxr[kk][2], a, a2, 0, 0, 0);
                a3 = __builtin_amdgcn_mfma_f32_16x16x32_bf16(wxr[kk][3], a, a3, 0, 0, 0);
            } else {
                bf16x8 w0 = *(const bf16x8*)&wlds[0][alr][k];
                bf16x8 w1 = *(const bf16x8*)&wlds[1][alr][k];
                bf16x8 w2 = *(const bf16x8*)&wlds[2][alr][k];
                bf16x8 w3 = *(const bf16x8*)&wlds[3][alr][k];
                a0 = __builtin_amdgcn_mfma_f32_16x16x32_bf16(w0, a, a0, 0, 0, 0);
                a1 = __builtin_amdgcn_mfma_f32_16x16x32_bf16(w1, a, a1, 0, 0, 0);
                a2 = __builtin_amdgcn_mfma_f32_16x16x32_bf16(w2, a, a2, 0, 0, 0);
                a3 = __builtin_amdgcn_mfma_f32_16x16x32_bf16(w3, a, a3, 0, 0, 0);
            }
        }

        // gates, h @ V part (K = 512..1024); h read coherent from LLC
        #pragma unroll
        for (int kk = 0; kk < 16; ++kk) {
            const int k = kk * 32 + kbase;
            const u64* ph = (const u64*)(hp + hoff + k);
            union { u64 u[2]; bf16x8 v; } ha;
            ha.u[0] = coh_load(ph);
            ha.u[1] = coh_load(ph + 1);
            bf16x8 w0 = *(const bf16x8*)&wlds[0][alr][512 + k];
            bf16x8 w1 = *(const bf16x8*)&wlds[1][alr][512 + k];
            bf16x8 w2 = *(const bf16x8*)&wlds[2][alr][512 + k];
            bf16x8 w3 = *(const bf16x8*)&wlds[3][alr][512 + k];
            a0 = __builtin_amdgcn_mfma_f32_16x16x32_bf16(w0, ha.v, a0, 0, 0, 0);
            a1 = __builtin_amdgcn_mfma_f32_16x16x32_bf16(w1, ha.v, a1, 0, 0, 0);
            a2 = __builtin_amdgcn_mfma_f32_16x16x32_bf16(w2, ha.v, a2, 0, 0, 0);
            a3 = __builtin_amdgcn_mfma_f32_16x16x32_bf16(w3, ha.v, a3, 0, 0, 0);
        }

        // ctilde: (c_{t-1} * f_att_t) @ W_e  (cp pre-scaled; weights in regs)
        #pragma unroll
        for (int kk = 0; kk < 16; ++kk) {
            const int k = kk * 32 + kbase;
            const u64* pc = (const u64*)(cp + hoff + k);
            union { u64 u[2]; bf16x8 v; } ca;
            ca.u[0] = coh_load(pc);
            ca.u[1] = coh_load(pc + 1);
            a4 = __builtin_amdgcn_mfma_f32_16x16x32_bf16(wer[kk], ca.v, a4, 0, 0, 0);
        }

        // elementwise: lane holds j = jbase..jbase+3 for batch row brow
        const float fa = (t + 1 < S_SZ) ? tsrow[t + 1] : 0.f;
        f32x4 hv4, cv4;
        union { bf16x4 v; u64 u; } ph8, pc8;
        #pragma unroll
        for (int e = 0; e < 4; ++e) {
            float it = sigmoidf_(a0[e] + Bi4[e]);
            float ft = sigmoidf_(a1[e] + Bf4[e]);
            float gt = tanhf_(a2[e] + Bc4[e]);
            float ot = sigmoidf_(a3[e] + Bo4[e]);
            float ctl = tanhf_(a4[e] + Be4[e]);
            float cv = ft * ctl + it * gt;
            float hv = ot * tanhf_(cv);
            hv4[e] = hv; cv4[e] = cv;
            ph8.v[e] = (__bf16)hv;
            pc8.v[e] = (__bf16)(cv * fa);
        }
        *(f32x4*)(outrow + (size_t)t * H_SZ) = hv4;
        coh_store((u64*)(hnx + hoff + jbase), ph8.u);
        coh_store((u64*)(cnx + hoff + jbase), pc8.u);
        if (t == S_SZ - 1) {
            float* tail = out + (size_t)B_SZ * S_SZ * H_SZ;
            *(f32x4*)(tail + hoff + jbase) = hv4;
            *(f32x4*)(tail + (size_t)B_SZ * H_SZ + hoff + jbase) = cv4;
        }

        // per-row-group barrier (32 WGs sharing rblk), monotonic counter.
        // sc1 stores are LLC-visible once vmcnt drains -> no fences needed.
        if (t < S_SZ - 1) {
            asm volatile("s_waitcnt vmcnt(0)" ::: "memory");
            __syncthreads();
            if (tid == 0) {
                __hip_atomic_fetch_add(&cnts[rblk * 16], 1, __ATOMIC_RELAXED,
                                       __HIP_MEMORY_SCOPE_AGENT);
                const int target = 32 * (t + 1);
                while (__hip_atomic_load(&cnts[rblk * 16], __ATOMIC_RELAXED,
                                         __HIP_MEMORY_SCOPE_AGENT) < target) {
                    __builtin_amdgcn_s_sleep(1);
                }
            }
            __syncthreads();
        }
    }
}

extern "C" void kernel_launch(void* const* d_in, const int* in_sizes, int n_in,
                              void* d_out, int out_size, void* d_ws, size_t ws_size,
                              hipStream_t stream) {
    const float* x  = (const float*)d_in[0];
    const float* ts = (const float*)d_in[1];
    const float* We = (const float*)d_in[2];
    const float* be = (const float*)d_in[3];
    const float* Ui = (const float*)d_in[4];
    const float* Vi = (const float*)d_in[5];
    const float* bi = (const float*)d_in[6];
    const float* Uf = (const float*)d_in[7];
    const float* Vf = (const float*)d_in[8];
    const float* bf = (const float*)d_in[9];
    const float* Uc = (const float*)d_in[10];
    const float* Vc = (const float*)d_in[11];
    const float* bc = (const float*)d_in[12];
    const float* Uo = (const float*)d_in[13];
    const float* Vo = (const float*)d_in[14];
    const float* bo = (const float*)d_in[15];

    char* ws = (char*)d_ws;
    int* cnts = (int*)ws;
    __bf16* state = (__bf16*)(ws + 512);
    __bf16* GwT = (__bf16*)(ws + GWT_OFF_BYTES);
    __bf16* WeT = (__bf16*)(ws + WET_OFF_BYTES);

    // zero barrier counters + parity-0 state (h0 = c0 = 0)
    hipMemsetAsync(ws, 0, 512 + 2 * 524288, stream);
    prep_weights<<<2560, 256, 0, stream>>>(We, Ui, Vi, Uf, Vf, Uc, Vc, Uo, Vo, GwT, WeT);
    lstm_persist<<<256, 256, 0, stream>>>(x, ts, bi, bf, bc, bo, be, GwT, WeT,
                                          state, cnts, (float*)d_out);
}

// Round 4
// 3225.005 us; speedup vs baseline: 2.8674x; 1.4855x over previous
//
#include <hip/hip_runtime.h>

#define B_SZ 512
#define S_SZ 256
#define D_SZ 512
#define H_SZ 512

typedef __bf16 bf16x8 __attribute__((ext_vector_type(8)));
typedef __bf16 bf16x4 __attribute__((ext_vector_type(4)));
typedef float f32x4 __attribute__((ext_vector_type(4)));
typedef unsigned long long u64;

// ---------------- ws layout (bytes) ----------------
// [0, 512)        : 8 group barrier counters (64B stride)
// [512, +1MB)     : state parity 0: h0 (512x512 bf16) then cf0 (c*f_att)
// [+1MB, +2MB)    : state parity 1
// [2097664, +4MB) : GwT 4*512*1024 bf16 (g, j, k)
// [6291968, +.5MB): WeT 512*512 bf16 (j, k)
#define STATE_PAR_ELEMS (2 * H_SZ * B_SZ)
#define GWT_OFF_BYTES 2097664
#define WET_OFF_BYTES 6291968

// XOR swizzle: 2-way max bank aliasing on ds_read_b128 (free per m136)
#define SWZ(j, k) ((k) ^ (((j) & 7) << 3) ^ ((((j) >> 3) & 1) << 6))

__device__ __forceinline__ float sigmoidf_(float v) {
    return 1.f / (1.f + __expf(-v));
}
__device__ __forceinline__ float tanhf_(float v) {
    return 1.f - 2.f / (1.f + __expf(2.f * v));
}

// coherent LLC-level accesses; relaxed agent atomics -> global_load/store with
// sc bits, NO cache flushes, and (critically) compiler-correct vmcnt tracking.
__device__ __forceinline__ u64 coh_load(const u64* p) {
    return __hip_atomic_load(p, __ATOMIC_RELAXED, __HIP_MEMORY_SCOPE_AGENT);
}
__device__ __forceinline__ void coh_store(u64* p, u64 v) {
    __hip_atomic_store(p, v, __ATOMIC_RELAXED, __HIP_MEMORY_SCOPE_AGENT);
}

__global__ __launch_bounds__(256) void prep_weights(
    const float* __restrict__ We,
    const float* __restrict__ Ui, const float* __restrict__ Vi,
    const float* __restrict__ Uf, const float* __restrict__ Vf,
    const float* __restrict__ Uc, const float* __restrict__ Vc,
    const float* __restrict__ Uo, const float* __restrict__ Vo,
    __bf16* __restrict__ GwT, __bf16* __restrict__ WeT)
{
    const int bid = blockIdx.x;
    const int tid = threadIdx.x;
    if (bid < 2048) {
        const int g = bid >> 9;
        const int j = bid & 511;
        const float* U = (g == 0) ? Ui : (g == 1) ? Uf : (g == 2) ? Uc : Uo;
        const float* V = (g == 0) ? Vi : (g == 1) ? Vf : (g == 2) ? Vc : Vo;
        __bf16* dst = GwT + ((size_t)(g * 512 + j) << 10);
        for (int k = tid; k < 1024; k += 256) {
            float v = (k < 512) ? U[k * 512 + j] : V[(k - 512) * 512 + j];
            dst[k] = (__bf16)v;
        }
    } else {
        const int j = bid - 2048;
        __bf16* dst = WeT + ((size_t)j << 9);
        for (int k = tid; k < 512; k += 256) {
            dst[k] = (__bf16)We[k * 512 + j];
        }
    }
}

// Persistent recurrent kernel. 256 WGs x 256 thr, 1 WG/CU (144KB LDS).
// WG (rblk=bid&7, cblk=bid>>3): batch rows [rblk*64,+64) x cols [cblk*16,+16).
// Per-step: issue 64 coherent state u64-loads -> x@U MFMA (regs+LDS, hides LLC
// latency) -> h@V + cf@We (compiler waits on state regs) -> x[t+1] prefetch ->
// elementwise -> stores -> convert x -> state stores -> group barrier.
__global__ __launch_bounds__(256, 1) void lstm_persist(
    const float* __restrict__ x, const float* __restrict__ tseq,
    const float* __restrict__ b_i, const float* __restrict__ b_f,
    const float* __restrict__ b_c, const float* __restrict__ b_o,
    const float* __restrict__ b_e,
    const __bf16* __restrict__ GwT, const __bf16* __restrict__ WeT,
    __bf16* __restrict__ state, int* __restrict__ cnts,
    float* __restrict__ out)
{
    __shared__ __align__(16) __bf16 wlds[4][16][1024];
    __shared__ __align__(16) __bf16 welds[16][512];

    const int tid = threadIdx.x;
    const int bid = blockIdx.x;
    const int rblk = bid & 7;
    const int cblk = bid >> 3;
    const int j0 = cblk << 4;
    const int wave = tid >> 6;
    const int lane = tid & 63;
    const int alr = lane & 15;   // weight row j (A-frag row)
    const int hq = lane >> 4;    // k-subgroup / C j-quad
    const int kbase = hq * 8;

    // ---- stage weights into LDS, swizzled (once) ----
    for (int e = tid * 8; e < 4 * 16 * 1024; e += 256 * 8) {
        const int g = e >> 14;
        const int j = (e >> 10) & 15;
        const int k = e & 1023;
        *(uint4*)&wlds[g][j][SWZ(j, k)] =
            *(const uint4*)&GwT[((size_t)(g * 512 + j0 + j) << 10) + k];
    }
    for (int e = tid * 8; e < 16 * 512; e += 256 * 8) {
        const int j = e >> 9;
        const int k = e & 511;
        *(uint4*)&welds[j][SWZ(j, k)] =
            *(const uint4*)&WeT[((size_t)(j0 + j) << 9) + k];
    }
    __syncthreads();

    // gates k<256 weight fragments in registers (128 VGPR)
    bf16x8 wxr[8][4];
    #pragma unroll
    for (int kk = 0; kk < 8; ++kk)
        #pragma unroll
        for (int g = 0; g < 4; ++g)
            wxr[kk][g] = *(const bf16x8*)&wlds[g][alr][SWZ(alr, kk * 32 + kbase)];

    const int brow = rblk * 64 + wave * 16 + alr;   // batch row
    const int jbase = j0 + hq * 4;                   // 4 consecutive j (C rows)
    const f32x4 Bi4 = *(const f32x4*)(b_i + jbase);
    const f32x4 Bf4 = *(const f32x4*)(b_f + jbase);
    const f32x4 Bc4 = *(const f32x4*)(b_c + jbase);
    const f32x4 Bo4 = *(const f32x4*)(b_o + jbase);
    const f32x4 Be4 = *(const f32x4*)(b_e + jbase);

    const float* xrow = x + (size_t)brow * S_SZ * D_SZ;
    const float* tsrow = tseq + (size_t)brow * S_SZ;
    const size_t hoff = (size_t)brow * H_SZ;
    float* outrow = out + (size_t)brow * S_SZ * H_SZ + jbase;

    // prologue: load + convert x[0] (xf transient, dies here)
    bf16x8 xbf[16];
    {
        f32x4 xf[32];
        #pragma unroll
        for (int kk = 0; kk < 16; ++kk) {
            xf[2 * kk]     = *(const f32x4*)(xrow + kk * 32 + kbase);
            xf[2 * kk + 1] = *(const f32x4*)(xrow + kk * 32 + kbase + 4);
        }
        #pragma unroll
        for (int kk = 0; kk < 16; ++kk) {
            f32x4 u = xf[2 * kk], v = xf[2 * kk + 1];
            bf16x8 a;
            a[0] = (__bf16)u[0]; a[1] = (__bf16)u[1]; a[2] = (__bf16)u[2]; a[3] = (__bf16)u[3];
            a[4] = (__bf16)v[0]; a[5] = (__bf16)v[1]; a[6] = (__bf16)v[2]; a[7] = (__bf16)v[3];
            xbf[kk] = a;
        }
    }

    for (int t = 0; t < S_SZ; ++t) {
        const __bf16* hp = state + (size_t)(t & 1) * STATE_PAR_ELEMS;
        const __bf16* cp = hp + (size_t)H_SZ * B_SZ;
        __bf16* hnx = state + (size_t)((t + 1) & 1) * STATE_PAR_ELEMS;
        __bf16* cnx = hnx + (size_t)H_SZ * B_SZ;

        // 1. issue all 64 coherent state loads (h/c interleaved, oldest-first;
        //    atomics are ordered -> scheduler keeps them ahead of the ds_reads)
        union HU { u64 u[2]; bf16x8 v; };
        HU hs[16], cs[16];
        #pragma unroll
        for (int kk = 0; kk < 16; ++kk) {
            const u64* ph = (const u64*)(hp + hoff + kbase + kk * 32);
            const u64* pc = (const u64*)(cp + hoff + kbase + kk * 32);
            hs[kk].u[0] = coh_load(ph);
            hs[kk].u[1] = coh_load(ph + 1);
            cs[kk].u[0] = coh_load(pc);
            cs[kk].u[1] = coh_load(pc + 1);
        }

        f32x4 a0 = {0,0,0,0}, a1 = {0,0,0,0}, a2 = {0,0,0,0}, a3 = {0,0,0,0}, a4 = {0,0,0,0};

        // 2. x@U MFMAs while state loads fly (kk<8 weights from regs)
        #pragma unroll
        for (int kk = 0; kk < 16; ++kk) {
            bf16x8 w0, w1, w2, w3;
            if (kk < 8) {
                w0 = wxr[kk][0]; w1 = wxr[kk][1]; w2 = wxr[kk][2]; w3 = wxr[kk][3];
            } else {
                const int k = SWZ(alr, kk * 32 + kbase);
                w0 = *(const bf16x8*)&wlds[0][alr][k];
                w1 = *(const bf16x8*)&wlds[1][alr][k];
                w2 = *(const bf16x8*)&wlds[2][alr][k];
                w3 = *(const bf16x8*)&wlds[3][alr][k];
            }
            a0 = __builtin_amdgcn_mfma_f32_16x16x32_bf16(w0, xbf[kk], a0, 0, 0, 0);
            a1 = __builtin_amdgcn_mfma_f32_16x16x32_bf16(w1, xbf[kk], a1, 0, 0, 0);
            a2 = __builtin_amdgcn_mfma_f32_16x16x32_bf16(w2, xbf[kk], a2, 0, 0, 0);
            a3 = __builtin_amdgcn_mfma_f32_16x16x32_bf16(w3, xbf[kk], a3, 0, 0, 0);
        }

        // 3. h@V + cf@W_e (compiler inserts per-use vmcnt waits on hs/cs)
        #pragma unroll
        for (int kk = 0; kk < 16; ++kk) {
            const int k = SWZ(alr, 512 + kk * 32 + kbase);
            bf16x8 w0 = *(const bf16x8*)&wlds[0][alr][k];
            bf16x8 w1 = *(const bf16x8*)&wlds[1][alr][k];
            bf16x8 w2 = *(const bf16x8*)&wlds[2][alr][k];
            bf16x8 w3 = *(const bf16x8*)&wlds[3][alr][k];
            bf16x8 we = *(const bf16x8*)&welds[alr][SWZ(alr, kk * 32 + kbase)];
            a0 = __builtin_amdgcn_mfma_f32_16x16x32_bf16(w0, hs[kk].v, a0, 0, 0, 0);
            a1 = __builtin_amdgcn_mfma_f32_16x16x32_bf16(w1, hs[kk].v, a1, 0, 0, 0);
            a2 = __builtin_amdgcn_mfma_f32_16x16x32_bf16(w2, hs[kk].v, a2, 0, 0, 0);
            a3 = __builtin_amdgcn_mfma_f32_16x16x32_bf16(w3, hs[kk].v, a3, 0, 0, 0);
            a4 = __builtin_amdgcn_mfma_f32_16x16x32_bf16(we, cs[kk].v, a4, 0, 0, 0);
        }

        // 4. issue x[t+1] loads (latency hides under elementwise + stores)
        const int tp = (t + 1 < S_SZ) ? t + 1 : t;
        const float* xpn = xrow + (size_t)tp * D_SZ;
        f32x4 xf[32];
        #pragma unroll
        for (int kk = 0; kk < 16; ++kk) {
            xf[2 * kk]     = *(const f32x4*)(xpn + kk * 32 + kbase);
            xf[2 * kk + 1] = *(const f32x4*)(xpn + kk * 32 + kbase + 4);
        }

        // 5. elementwise: lane holds j = jbase..jbase+3 for batch row brow
        const float fa = (t + 1 < S_SZ) ? tsrow[t + 1] : 0.f;
        f32x4 hv4, cv4;
        union { bf16x4 v; u64 u; } ph8, pc8;
        #pragma unroll
        for (int e = 0; e < 4; ++e) {
            float it = sigmoidf_(a0[e] + Bi4[e]);
            float ft = sigmoidf_(a1[e] + Bf4[e]);
            float gt = tanhf_(a2[e] + Bc4[e]);
            float ot = sigmoidf_(a3[e] + Bo4[e]);
            float ctl = tanhf_(a4[e] + Be4[e]);
            float cv = ft * ctl + it * gt;
            float hv = ot * tanhf_(cv);
            hv4[e] = hv; cv4[e] = cv;
            ph8.v[e] = (__bf16)hv;
            pc8.v[e] = (__bf16)(cv * fa);
        }
        __builtin_nontemporal_store(hv4, (f32x4*)(outrow + (size_t)t * H_SZ));
        if (t == S_SZ - 1) {
            float* tail = out + (size_t)B_SZ * S_SZ * H_SZ;
            *(f32x4*)(tail + hoff + jbase) = hv4;
            *(f32x4*)(tail + (size_t)B_SZ * H_SZ + hoff + jbase) = cv4;
        }

        // 6. convert x[t+1] (single wait; store issue above overlapped latency)
        #pragma unroll
        for (int kk = 0; kk < 16; ++kk) {
            f32x4 u = xf[2 * kk], v = xf[2 * kk + 1];
            bf16x8 a;
            a[0] = (__bf16)u[0]; a[1] = (__bf16)u[1]; a[2] = (__bf16)u[2]; a[3] = (__bf16)u[3];
            a[4] = (__bf16)v[0]; a[5] = (__bf16)v[1]; a[6] = (__bf16)v[2]; a[7] = (__bf16)v[3];
            xbf[kk] = a;
        }

        // 7. publish state (coherent stores; drained by syncthreads' vmcnt(0))
        coh_store((u64*)(hnx + hoff + jbase), ph8.u);
        coh_store((u64*)(cnx + hoff + jbase), pc8.u);

        // 8. group barrier (32 WGs sharing rblk), monotonic counter
        if (t < S_SZ - 1) {
            __syncthreads();   // emits s_waitcnt vmcnt(0) before s_barrier
            if (tid == 0) {
                __hip_atomic_fetch_add(&cnts[rblk * 16], 1, __ATOMIC_RELAXED,
                                       __HIP_MEMORY_SCOPE_AGENT);
                const int target = 32 * (t + 1);
                while (__hip_atomic_load(&cnts[rblk * 16], __ATOMIC_RELAXED,
                                         __HIP_MEMORY_SCOPE_AGENT) < target) {
                    __builtin_amdgcn_s_sleep(1);
                }
            }
            __syncthreads();
        }
    }
}

extern "C" void kernel_launch(void* const* d_in, const int* in_sizes, int n_in,
                              void* d_out, int out_size, void* d_ws, size_t ws_size,
                              hipStream_t stream) {
    const float* x  = (const float*)d_in[0];
    const float* ts = (const float*)d_in[1];
    const float* We = (const float*)d_in[2];
    const float* be = (const float*)d_in[3];
    const float* Ui = (const float*)d_in[4];
    const float* Vi = (const float*)d_in[5];
    const float* bi = (const float*)d_in[6];
    const float* Uf = (const float*)d_in[7];
    const float* Vf = (const float*)d_in[8];
    const float* bf = (const float*)d_in[9];
    const float* Uc = (const float*)d_in[10];
    const float* Vc = (const float*)d_in[11];
    const float* bc = (const float*)d_in[12];
    const float* Uo = (const float*)d_in[13];
    const float* Vo = (const float*)d_in[14];
    const float* bo = (const float*)d_in[15];

    char* ws = (char*)d_ws;
    int* cnts = (int*)ws;
    __bf16* state = (__bf16*)(ws + 512);
    __bf16* GwT = (__bf16*)(ws + GWT_OFF_BYTES);
    __bf16* WeT = (__bf16*)(ws + WET_OFF_BYTES);

    // zero barrier counters + parity-0 state (h0 = c0 = 0)
    hipMemsetAsync(ws, 0, 512 + 2 * 524288, stream);
    prep_weights<<<2560, 256, 0, stream>>>(We, Ui, Vi, Uf, Vf, Uc, Vc, Uo, Vo, GwT, WeT);
    lstm_persist<<<256, 256, 0, stream>>>(x, ts, bi, bf, bc, bo, be, GwT, WeT,
                                          state, cnts, (float*)d_out);
}